// Round 1
// baseline (1430.851 us; speedup 1.0000x reference)
//
#include <hip/hip_runtime.h>
#include <math.h>

// GATv2 x2 + projection, fp32 reference-faithful implementation.
// Pipeline: CSR build -> conv1 (3 GEMM, edge logits, softmax, aggregate+relu)
//           -> conv2 (3 GEMM, edge logits, softmax, aggregate+relu+headsum)
//           -> final GEMM (relu skipped: sum-of-relus >= 0).

static constexpr int HEADS = 2;

// ---------------- CSR build ----------------
__global__ void k_count(const int* __restrict__ dst, int* __restrict__ deg, int E) {
  int t = blockIdx.x * blockDim.x + threadIdx.x;
  if (t < E) atomicAdd(&deg[dst[t]], 1);
}

__global__ void k_scan(const int* __restrict__ deg, int* __restrict__ off, int n) {
  __shared__ int part[1024];
  int t = threadIdx.x;
  int per = (n + 1023) >> 10;
  int s0 = t * per, s1 = min(s0 + per, n);
  int s = 0;
  for (int i = s0; i < s1; ++i) s += deg[i];
  part[t] = s;
  __syncthreads();
  for (int d = 1; d < 1024; d <<= 1) {
    int v = (t >= d) ? part[t - d] : 0;
    __syncthreads();
    part[t] += v;
    __syncthreads();
  }
  int base = (t == 0) ? 0 : part[t - 1];
  for (int i = s0; i < s1; ++i) { off[i] = base; base += deg[i]; }
  if (t == 1023) off[n] = part[1023];
}

__global__ void k_scatter(const int* __restrict__ dst, const int* __restrict__ off,
                          int* __restrict__ cursor, int* __restrict__ elist, int E) {
  int t = blockIdx.x * blockDim.x + threadIdx.x;
  if (t < E) {
    int d = dst[t];
    int p = atomicAdd(&cursor[d], 1);
    elist[off[d] + p] = t;
  }
}

// ---------------- GEMM: C[M,Ncol] = A[M,K] @ W[K,Ncol] + bias ----------------
__global__ __launch_bounds__(256) void k_gemm(const float* __restrict__ A,
                                              const float* __restrict__ W,
                                              const float* __restrict__ bias,
                                              float* __restrict__ C,
                                              int M, int K, int Ncol) {
  __shared__ __align__(16) float As[16][68];  // [k][m], padded (68%4==0 keeps f4 align)
  __shared__ __align__(16) float Ws[16][68];  // [k][n]
  int bm = blockIdx.x * 64, bn = blockIdx.y * 64;
  int t = threadIdx.x;
  int ty = t >> 4, tx = t & 15;
  float acc[4][4] = {};
  int ar = t >> 2, akq = t & 3;   // A tile: row 0..63, k-quad 0..3
  int wr = t >> 4, wnq = t & 15;  // W tile: k-row 0..15, n-quad 0..15

  for (int k0 = 0; k0 < K; k0 += 16) {
    float4 av = make_float4(0.f, 0.f, 0.f, 0.f);
    int am = bm + ar;
    if (am < M) av = *reinterpret_cast<const float4*>(A + (size_t)am * K + k0 + akq * 4);
    As[akq * 4 + 0][ar] = av.x;
    As[akq * 4 + 1][ar] = av.y;
    As[akq * 4 + 2][ar] = av.z;
    As[akq * 4 + 3][ar] = av.w;
    float4 wv = *reinterpret_cast<const float4*>(W + (size_t)(k0 + wr) * Ncol + bn + wnq * 4);
    *reinterpret_cast<float4*>(&Ws[wr][wnq * 4]) = wv;
    __syncthreads();
#pragma unroll
    for (int k = 0; k < 16; ++k) {
      float4 a = *reinterpret_cast<const float4*>(&As[k][ty * 4]);
      float4 b = *reinterpret_cast<const float4*>(&Ws[k][tx * 4]);
      float avv[4] = {a.x, a.y, a.z, a.w};
      float bvv[4] = {b.x, b.y, b.z, b.w};
#pragma unroll
      for (int i = 0; i < 4; ++i)
#pragma unroll
        for (int j = 0; j < 4; ++j) acc[i][j] += avv[i] * bvv[j];
    }
    __syncthreads();
  }
#pragma unroll
  for (int i = 0; i < 4; ++i) {
    int m = bm + ty * 4 + i;
    if (m < M) {
#pragma unroll
      for (int j = 0; j < 4; ++j) {
        int n = bn + tx * 4 + j;
        C[(size_t)m * Ncol + n] = acc[i][j] + bias[n];
      }
    }
  }
}

// ---------------- per-edge attention logits ----------------
// e[e,h] = sum_d attn[h,d] * leaky_relu(fs[src,h,d] + fd[dst,h,d], 0.2)
template <int D>
__global__ __launch_bounds__(256) void k_edge_logit(const float* __restrict__ fs,
                                                    const float* __restrict__ fd,
                                                    const int* __restrict__ src,
                                                    const int* __restrict__ dst,
                                                    const float* __restrict__ attn,
                                                    float* __restrict__ elog, int E) {
  int wid = blockIdx.x * (blockDim.x >> 6) + (threadIdx.x >> 6);
  if (wid >= E) return;
  int lane = threadIdx.x & 63;
  int s = src[wid], d = dst[wid];
  constexpr int PER = D / 64;
#pragma unroll
  for (int h = 0; h < HEADS; ++h) {
    const float* ps = fs + (size_t)s * (HEADS * D) + h * D + lane * PER;
    const float* pd = fd + (size_t)d * (HEADS * D) + h * D + lane * PER;
    const float* pa = attn + h * D + lane * PER;
    float acc = 0.f;
#pragma unroll
    for (int i = 0; i < PER; i += 4) {
      float4 a = *reinterpret_cast<const float4*>(ps + i);
      float4 b = *reinterpret_cast<const float4*>(pd + i);
      float4 w = *reinterpret_cast<const float4*>(pa + i);
      float v;
      v = a.x + b.x; v = v > 0.f ? v : 0.2f * v; acc += v * w.x;
      v = a.y + b.y; v = v > 0.f ? v : 0.2f * v; acc += v * w.y;
      v = a.z + b.z; v = v > 0.f ? v : 0.2f * v; acc += v * w.z;
      v = a.w + b.w; v = v > 0.f ? v : 0.2f * v; acc += v * w.w;
    }
#pragma unroll
    for (int o = 32; o > 0; o >>= 1) acc += __shfl_down(acc, o, 64);
    if (lane == 0) elog[(size_t)wid * HEADS + h] = acc;
  }
}

// ---------------- per-(node,head) softmax stats ----------------
__global__ void k_stats(const float* __restrict__ elog, const int* __restrict__ off,
                        const int* __restrict__ elist, float* __restrict__ nmax,
                        float* __restrict__ nden, int n) {
  int t = blockIdx.x * blockDim.x + threadIdx.x;
  if (t >= n * HEADS) return;
  int node = t >> 1, h = t & 1;
  int b = off[node], e = off[node + 1];
  float m = -1e30f;
  for (int i = b; i < e; ++i) m = fmaxf(m, elog[(size_t)elist[i] * HEADS + h]);
  float s = 0.f;
  for (int i = b; i < e; ++i) s += __expf(elog[(size_t)elist[i] * HEADS + h] - m);
  nmax[t] = m;
  nden[t] = s;
}

// ---------------- per-edge alpha (in place on elog) ----------------
__global__ void k_alpha(float* __restrict__ elog, const int* __restrict__ dst,
                        const float* __restrict__ nmax, const float* __restrict__ nden, int E) {
  int t = blockIdx.x * blockDim.x + threadIdx.x;
  if (t >= E * HEADS) return;
  int e = t >> 1, h = t & 1;
  int d = dst[e];
  elog[t] = __expf(elog[t] - nmax[d * HEADS + h]) / nden[d * HEADS + h];
}

// ---------------- attention-weighted aggregation ----------------
// out = relu(segsum(fs[src]*alpha) + res); SUMH additionally sums heads.
template <int D, bool SUMH>
__global__ __launch_bounds__(256) void k_aggregate(const float* __restrict__ fs,
                                                   const float* __restrict__ res,
                                                   const float* __restrict__ alpha,
                                                   const int* __restrict__ src,
                                                   const int* __restrict__ off,
                                                   const int* __restrict__ elist,
                                                   float* __restrict__ out) {
  constexpr int W = HEADS * D;
  constexpr int OPT = W / 256;
  int n = blockIdx.x;
  int t = threadIdx.x;
  int b = off[n], e = off[n + 1];
  float acc[OPT];
#pragma unroll
  for (int j = 0; j < OPT; ++j) acc[j] = 0.f;
  for (int i = b; i < e; ++i) {
    int ed = elist[i];
    int s = src[ed];
    float a0 = alpha[(size_t)ed * HEADS + 0];
    float a1 = alpha[(size_t)ed * HEADS + 1];
    const float* p = fs + (size_t)s * W;
#pragma unroll
    for (int j = 0; j < OPT; ++j) {
      int o = t + j * 256;
      acc[j] += p[o] * ((o < D) ? a0 : a1);
    }
  }
  const float* r = res + (size_t)n * W;
  if constexpr (!SUMH) {
#pragma unroll
    for (int j = 0; j < OPT; ++j) {
      int o = t + j * 256;
      float v = acc[j] + r[o];
      out[(size_t)n * W + o] = v > 0.f ? v : 0.f;
    }
  } else {
#pragma unroll
    for (int j = 0; j < OPT / 2; ++j) {
      int o0 = t + j * 256;      // head 0 element d=o0
      int o1 = o0 + D;           // head 1, same d
      float v0 = acc[j] + r[o0];           v0 = v0 > 0.f ? v0 : 0.f;
      float v1 = acc[j + OPT / 2] + r[o1]; v1 = v1 > 0.f ? v1 : 0.f;
      out[(size_t)n * D + o0] = v0 + v1;   // final relu is a no-op (v0+v1 >= 0)
    }
  }
}

extern "C" void kernel_launch(void* const* d_in, const int* in_sizes, int n_in,
                              void* d_out, int out_size, void* d_ws, size_t ws_size,
                              hipStream_t stream) {
  const float* x    = (const float*)d_in[0];
  const int*   src  = (const int*)d_in[1];
  const int*   dst  = (const int*)d_in[2];
  const float* W1s  = (const float*)d_in[3];
  const float* b1s  = (const float*)d_in[4];
  const float* W1d  = (const float*)d_in[5];
  const float* b1d  = (const float*)d_in[6];
  const float* at1  = (const float*)d_in[7];
  const float* W1r  = (const float*)d_in[8];
  const float* b1r  = (const float*)d_in[9];
  const float* W2s  = (const float*)d_in[10];
  const float* b2s  = (const float*)d_in[11];
  const float* W2d  = (const float*)d_in[12];
  const float* b2d  = (const float*)d_in[13];
  const float* at2  = (const float*)d_in[14];
  const float* W2r  = (const float*)d_in[15];
  const float* b2r  = (const float*)d_in[16];
  const float* Wp   = (const float*)d_in[17];
  const float* bp   = (const float*)d_in[18];
  float* out = (float*)d_out;

  const int N = in_sizes[0] / 1024;  // 10000
  const int E = in_sizes[1];         // 160000

  // workspace layout
  char* ws = (char*)d_ws;
  size_t NB = (size_t)N * 1024 * sizeof(float);  // big node buffer (conv2 width)
  size_t HB = (size_t)N * 512 * sizeof(float);   // hidden buffer
  size_t EB = (size_t)E * HEADS * sizeof(float);
  float* fs   = (float*)(ws);
  float* fd   = (float*)(ws + NB);
  float* res  = (float*)(ws + 2 * NB);
  float* h1   = (float*)(ws + 3 * NB);
  float* h2   = (float*)(ws + 3 * NB + HB);
  float* elog = (float*)(ws + 3 * NB + 2 * HB);
  float* nmax = (float*)(ws + 3 * NB + 2 * HB + EB);
  float* nden = nmax + (size_t)N * HEADS;
  int* deg    = (int*)(nden + (size_t)N * HEADS);
  int* off    = deg + N;
  int* cursor = off + N + 1;
  int* elist  = cursor + N;
  size_t need = (size_t)((char*)(elist + E) - ws);
  if (need > ws_size) return;  // workspace too small -> leave output poisoned

  // CSR build (per call; reused by both convs)
  hipMemsetAsync(deg, 0, (size_t)N * sizeof(int), stream);
  hipMemsetAsync(cursor, 0, (size_t)N * sizeof(int), stream);
  k_count<<<(E + 255) / 256, 256, 0, stream>>>(dst, deg, E);
  k_scan<<<1, 1024, 0, stream>>>(deg, off, N);
  k_scatter<<<(E + 255) / 256, 256, 0, stream>>>(dst, off, cursor, elist, E);

  // ---- conv1: IN=1024 -> H*D1 = 512 ----
  dim3 g1((N + 63) / 64, 512 / 64);
  k_gemm<<<g1, 256, 0, stream>>>(x, W1s, b1s, fs, N, 1024, 512);
  k_gemm<<<g1, 256, 0, stream>>>(x, W1d, b1d, fd, N, 1024, 512);
  k_gemm<<<g1, 256, 0, stream>>>(x, W1r, b1r, res, N, 1024, 512);
  k_edge_logit<256><<<(E + 3) / 4, 256, 0, stream>>>(fs, fd, src, dst, at1, elog, E);
  k_stats<<<(N * HEADS + 255) / 256, 256, 0, stream>>>(elog, off, elist, nmax, nden, N);
  k_alpha<<<(E * HEADS + 255) / 256, 256, 0, stream>>>(elog, dst, nmax, nden, E);
  k_aggregate<256, false><<<N, 256, 0, stream>>>(fs, res, elog, src, off, elist, h1);

  // ---- conv2: HID=512 -> H*D2 = 1024 ----
  dim3 g2((N + 63) / 64, 1024 / 64);
  k_gemm<<<g2, 256, 0, stream>>>(h1, W2s, b2s, fs, N, 512, 1024);
  k_gemm<<<g2, 256, 0, stream>>>(h1, W2d, b2d, fd, N, 512, 1024);
  k_gemm<<<g2, 256, 0, stream>>>(h1, W2r, b2r, res, N, 512, 1024);
  k_edge_logit<512><<<(E + 3) / 4, 256, 0, stream>>>(fs, fd, src, dst, at2, elog, E);
  k_stats<<<(N * HEADS + 255) / 256, 256, 0, stream>>>(elog, off, elist, nmax, nden, N);
  k_alpha<<<(E * HEADS + 255) / 256, 256, 0, stream>>>(elog, dst, nmax, nden, E);
  k_aggregate<512, true><<<N, 256, 0, stream>>>(fs, res, elog, src, off, elist, h2);

  // ---- projection (final relu skipped: h2 >= 0 elementwise) ----
  dim3 g3((N + 63) / 64, 512 / 64);
  k_gemm<<<g3, 256, 0, stream>>>(h2, Wp, bp, out, N, 512, 512);
}

// Round 2
// 414.990 us; speedup vs baseline: 3.4479x; 3.4479x over previous
//
#include <hip/hip_runtime.h>
#include <math.h>

static constexpr int HEADS = 2;

typedef unsigned int u32;
typedef unsigned short ushort_t;
typedef __attribute__((ext_vector_type(4))) short short4v;
typedef __attribute__((ext_vector_type(8))) short short8v;
typedef __attribute__((ext_vector_type(4))) float f32x4;

__device__ __forceinline__ unsigned short f2b(float f) {
  union { float f; u32 u; } v; v.f = f;
  u32 u = v.u;
  u32 r = (u + 0x7fffu + ((u >> 16) & 1u)) >> 16;  // RNE
  return (unsigned short)r;
}
__device__ __forceinline__ float b2f(unsigned short b) {
  union { u32 u; float f; } v; v.u = ((u32)b) << 16;
  return v.f;
}

__device__ __forceinline__ void async_copy16(const void* g, void* l) {
  __builtin_amdgcn_global_load_lds(
      (const __attribute__((address_space(1))) u32*)g,
      (__attribute__((address_space(3))) u32*)l, 16, 0, 0);
}

// ---------------- CSR build ----------------
__global__ void k_count(const int* __restrict__ dst, int* __restrict__ deg, int E) {
  int t = blockIdx.x * blockDim.x + threadIdx.x;
  if (t < E) atomicAdd(&deg[dst[t]], 1);
}

__global__ void k_scan(const int* __restrict__ deg, int* __restrict__ off, int n) {
  __shared__ int part[1024];
  int t = threadIdx.x;
  int per = (n + 1023) >> 10;
  int s0 = t * per, s1 = min(s0 + per, n);
  int s = 0;
  for (int i = s0; i < s1; ++i) s += deg[i];
  part[t] = s;
  __syncthreads();
  for (int d = 1; d < 1024; d <<= 1) {
    int v = (t >= d) ? part[t - d] : 0;
    __syncthreads();
    part[t] += v;
    __syncthreads();
  }
  int base = (t == 0) ? 0 : part[t - 1];
  for (int i = s0; i < s1; ++i) { off[i] = base; base += deg[i]; }
  if (t == 1023) off[n] = part[1023];
}

__global__ void k_scatter(const int* __restrict__ dst, const int* __restrict__ off,
                          int* __restrict__ cursor, int* __restrict__ elist, int E) {
  int t = blockIdx.x * blockDim.x + threadIdx.x;
  if (t < E) {
    int d = dst[t];
    int p = atomicAdd(&cursor[d], 1);
    elist[off[d] + p] = t;
  }
}

// ---------------- converts ----------------
__global__ void k_f2b(const float* __restrict__ x, unsigned short* __restrict__ xb, int n4) {
  int t = blockIdx.x * blockDim.x + threadIdx.x;
  if (t < n4) {
    float4 v = reinterpret_cast<const float4*>(x)[t];
    short4v o;
    o[0] = (short)f2b(v.x); o[1] = (short)f2b(v.y);
    o[2] = (short)f2b(v.z); o[3] = (short)f2b(v.w);
    reinterpret_cast<short4v*>(xb)[t] = o;
  }
}

// W [K,Ncol] f32 -> Wt [Ncol,K] bf16
__global__ __launch_bounds__(256) void k_convT(const float* __restrict__ W,
                                               unsigned short* __restrict__ Wt,
                                               int K, int Ncol) {
  __shared__ float tile[32][33];
  int bx = blockIdx.x * 32;  // Ncol dim
  int by = blockIdx.y * 32;  // K dim
  int tx = threadIdx.x & 31, ty = threadIdx.x >> 5;  // ty 0..7
#pragma unroll
  for (int i = 0; i < 32; i += 8)
    tile[ty + i][tx] = W[(size_t)(by + ty + i) * Ncol + bx + tx];
  __syncthreads();
#pragma unroll
  for (int i = 0; i < 32; i += 8)
    Wt[(size_t)(bx + ty + i) * K + by + tx] = f2b(tile[tx][ty + i]);
}

// ---------------- MFMA GEMM: C[M,Ncol] = A[M,K](bf16) @ Bt[Ncol,K](bf16)^T + bias ----------------
// 128x128 tile, BK=32, 4 waves (2x2 of 64x64), global_load_lds staging.
template <typename OutT>
__global__ __launch_bounds__(256) void k_gemm_mfma(const unsigned short* __restrict__ A,
                                                   const unsigned short* __restrict__ Bt,
                                                   const float* __restrict__ bias,
                                                   OutT* __restrict__ C,
                                                   int M, int K, int Ncol) {
  __shared__ __align__(16) unsigned short As[128 * 32];
  __shared__ __align__(16) unsigned short Bs[128 * 32];
  int t = threadIdx.x;
  int l = t & 63, w = t >> 6;
  int wr = w >> 1, wc = w & 1;
  int bm = blockIdx.x * 128, bn = blockIdx.y * 128;

  f32x4 acc[4][4] = {};

  int srow = t >> 2;            // 0..63
  int scol = (t & 3) * 8;       // bf16 element offset (16B)

  for (int k0 = 0; k0 < K; k0 += 32) {
    __syncthreads();
#pragma unroll
    for (int i = 0; i < 2; ++i) {
      int r = srow + i * 64;
      int gr = bm + r; if (gr >= M) gr = M - 1;
      async_copy16(A + (size_t)gr * K + k0 + scol, As + r * 32 + scol);
      int gb = bn + r;  // Ncol multiple of 128 -> in bounds
      async_copy16(Bt + (size_t)gb * K + k0 + scol, Bs + r * 32 + scol);
    }
    __syncthreads();

    short8v af[4], bf[4];
#pragma unroll
    for (int m = 0; m < 4; ++m)
      af[m] = *reinterpret_cast<const short8v*>(As + (wr * 64 + m * 16 + (l & 15)) * 32 + (l >> 4) * 8);
#pragma unroll
    for (int n = 0; n < 4; ++n)
      bf[n] = *reinterpret_cast<const short8v*>(Bs + (wc * 64 + n * 16 + (l & 15)) * 32 + (l >> 4) * 8);
#pragma unroll
    for (int m = 0; m < 4; ++m)
#pragma unroll
      for (int n = 0; n < 4; ++n)
        acc[m][n] = __builtin_amdgcn_mfma_f32_16x16x32_bf16(af[m], bf[n], acc[m][n], 0, 0, 0);
  }

#pragma unroll
  for (int m = 0; m < 4; ++m) {
#pragma unroll
    for (int q = 0; q < 4; ++q) {
      int row = bm + wr * 64 + m * 16 + (l >> 4) * 4 + q;
      if (row < M) {
#pragma unroll
        for (int n = 0; n < 4; ++n) {
          int col = bn + wc * 64 + n * 16 + (l & 15);
          float v = acc[m][n][q] + bias[col];
          if constexpr (sizeof(OutT) == 2) {
            C[(size_t)row * Ncol + col] = (OutT)f2b(v);
          } else {
            C[(size_t)row * Ncol + col] = (OutT)v;
          }
        }
      }
    }
  }
}

// ---------------- fused edge phase: logit + online softmax + aggregate + residual + relu ----------------
// One wave per (node, head). fs/fd bf16, res fp32, attn fp32.
// SUMH: sum the two heads' relu outputs (conv2 epilogue), write [N,D] bf16.
// else: write [N, H*D] bf16.
template <int D, bool SUMH>
__global__ __launch_bounds__(256) void k_edge_fused(const unsigned short* __restrict__ fs,
                                                    const unsigned short* __restrict__ fd,
                                                    const float* __restrict__ res,
                                                    const float* __restrict__ attn,
                                                    const int* __restrict__ src,
                                                    const int* __restrict__ off,
                                                    const int* __restrict__ elist,
                                                    unsigned short* __restrict__ outb,
                                                    int N) {
  constexpr int W = HEADS * D;
  constexpr int PER = D / 64;
  __shared__ float hs[2][SUMH ? D : 1];

  int w = threadIdx.x >> 6, l = threadIdx.x & 63;
  int node = blockIdx.x * 2 + (w >> 1);
  int h = w & 1;
  bool active = node < N;

  float fdv[PER], av[PER], acc[PER];
  float m = -1e30f, s = 0.f;

  if (active) {
    const unsigned short* pfd = fd + (size_t)node * W + h * D + l * PER;
    const float* pa = attn + h * D + l * PER;
#pragma unroll
    for (int j = 0; j < PER; ++j) { fdv[j] = b2f(pfd[j]); av[j] = pa[j]; acc[j] = 0.f; }

    int b = off[node], e = off[node + 1];
    for (int i = b; i < e; ++i) {
      int eid = elist[i];
      int sn = src[eid];
      const unsigned short* prow = fs + (size_t)sn * W + h * D + l * PER;
      float rowf[PER];
      if (PER == 8) {
        short8v rv = *reinterpret_cast<const short8v*>(prow);
#pragma unroll
        for (int j = 0; j < PER; ++j) rowf[j] = b2f((unsigned short)rv[j]);
      } else {
        short4v rv = *reinterpret_cast<const short4v*>(prow);
#pragma unroll
        for (int j = 0; j < PER; ++j) rowf[j] = b2f((unsigned short)rv[j]);
      }
      float part = 0.f;
#pragma unroll
      for (int j = 0; j < PER; ++j) {
        float v = rowf[j] + fdv[j];
        v = v > 0.f ? v : 0.2f * v;
        part += v * av[j];
      }
#pragma unroll
      for (int o = 1; o < 64; o <<= 1) part += __shfl_xor(part, o, 64);
      // online softmax update (uniform branch: part identical across lanes)
      if (part <= m) {
        float p = __expf(part - m);
        s += p;
#pragma unroll
        for (int j = 0; j < PER; ++j) acc[j] += p * rowf[j];
      } else {
        float c = (m == -1e30f) ? 0.f : __expf(m - part);
        s = s * c + 1.f;
#pragma unroll
        for (int j = 0; j < PER; ++j) acc[j] = acc[j] * c + rowf[j];
        m = part;
      }
    }

    float inv = (s > 0.f) ? 1.f / s : 0.f;
    const float* pr = res + (size_t)node * W + h * D + l * PER;
#pragma unroll
    for (int j = 0; j < PER; ++j) {
      float v = acc[j] * inv + pr[j];
      acc[j] = v > 0.f ? v : 0.f;  // relu
    }
  }

  if constexpr (SUMH) {
    if (active && h == 0) {
#pragma unroll
      for (int j = 0; j < PER; ++j) hs[w >> 1][l * PER + j] = acc[j];
    }
    __syncthreads();
    if (active && h == 1) {
      if (PER == 8) {
        short8v o;
#pragma unroll
        for (int j = 0; j < PER; ++j) o[j] = (short)f2b(acc[j] + hs[w >> 1][l * PER + j]);
        *reinterpret_cast<short8v*>(outb + (size_t)node * D + l * PER) = o;
      } else {
        short4v o;
#pragma unroll
        for (int j = 0; j < PER; ++j) o[j] = (short)f2b(acc[j] + hs[w >> 1][l * PER + j]);
        *reinterpret_cast<short4v*>(outb + (size_t)node * D + l * PER) = o;
      }
    }
  } else {
    if (active) {
      if (PER == 8) {
        short8v o;
#pragma unroll
        for (int j = 0; j < PER; ++j) o[j] = (short)f2b(acc[j]);
        *reinterpret_cast<short8v*>(outb + (size_t)node * W + h * D + l * PER) = o;
      } else {
        short4v o;
#pragma unroll
        for (int j = 0; j < PER; ++j) o[j] = (short)f2b(acc[j]);
        *reinterpret_cast<short4v*>(outb + (size_t)node * W + h * D + l * PER) = o;
      }
    }
  }
}

extern "C" void kernel_launch(void* const* d_in, const int* in_sizes, int n_in,
                              void* d_out, int out_size, void* d_ws, size_t ws_size,
                              hipStream_t stream) {
  const float* x    = (const float*)d_in[0];
  const int*   src  = (const int*)d_in[1];
  const int*   dst  = (const int*)d_in[2];
  const float* W1s  = (const float*)d_in[3];
  const float* b1s  = (const float*)d_in[4];
  const float* W1d  = (const float*)d_in[5];
  const float* b1d  = (const float*)d_in[6];
  const float* at1  = (const float*)d_in[7];
  const float* W1r  = (const float*)d_in[8];
  const float* b1r  = (const float*)d_in[9];
  const float* W2s  = (const float*)d_in[10];
  const float* b2s  = (const float*)d_in[11];
  const float* W2d  = (const float*)d_in[12];
  const float* b2d  = (const float*)d_in[13];
  const float* at2  = (const float*)d_in[14];
  const float* W2r  = (const float*)d_in[15];
  const float* b2r  = (const float*)d_in[16];
  const float* Wp   = (const float*)d_in[17];
  const float* bp   = (const float*)d_in[18];
  float* out = (float*)d_out;

  const int N = in_sizes[0] / 1024;  // 10000
  const int E = in_sizes[1];         // 160000

  // ---- workspace layout (bytes) ----
  char* ws = (char*)d_ws;
  size_t o = 0;
  auto alloc = [&](size_t bytes) { char* p = ws + o; o += (bytes + 255) & ~(size_t)255; return p; };
  unsigned short* xb  = (unsigned short*)alloc((size_t)N * 1024 * 2);
  unsigned short* w1s = (unsigned short*)alloc((size_t)512 * 1024 * 2);
  unsigned short* w1d = (unsigned short*)alloc((size_t)512 * 1024 * 2);
  unsigned short* w1r = (unsigned short*)alloc((size_t)512 * 1024 * 2);
  unsigned short* w2s = (unsigned short*)alloc((size_t)1024 * 512 * 2);
  unsigned short* w2d = (unsigned short*)alloc((size_t)1024 * 512 * 2);
  unsigned short* w2r = (unsigned short*)alloc((size_t)1024 * 512 * 2);
  unsigned short* wp  = (unsigned short*)alloc((size_t)512 * 512 * 2);
  unsigned short* fs  = (unsigned short*)alloc((size_t)N * 1024 * 2);
  unsigned short* fd  = (unsigned short*)alloc((size_t)N * 1024 * 2);
  float*          res = (float*)alloc((size_t)N * 1024 * 4);
  unsigned short* h1  = (unsigned short*)alloc((size_t)N * 512 * 2);
  unsigned short* h2  = (unsigned short*)alloc((size_t)N * 512 * 2);
  int* deg    = (int*)alloc((size_t)N * 4);
  int* offp   = (int*)alloc((size_t)(N + 1) * 4);
  int* cursor = (int*)alloc((size_t)N * 4);
  int* elist  = (int*)alloc((size_t)E * 4);
  if (o > ws_size) return;

  // ---- CSR build ----
  hipMemsetAsync(deg, 0, (size_t)N * 4, stream);
  hipMemsetAsync(cursor, 0, (size_t)N * 4, stream);
  k_count<<<(E + 255) / 256, 256, 0, stream>>>(dst, deg, E);
  k_scan<<<1, 1024, 0, stream>>>(deg, offp, N);
  k_scatter<<<(E + 255) / 256, 256, 0, stream>>>(dst, offp, cursor, elist, E);

  // ---- converts ----
  k_f2b<<<((N * 1024 / 4) + 255) / 256, 256, 0, stream>>>(x, xb, N * 1024 / 4);
  {
    dim3 gT1(512 / 32, 1024 / 32);   // W1*: [1024,512]
    k_convT<<<gT1, 256, 0, stream>>>(W1s, w1s, 1024, 512);
    k_convT<<<gT1, 256, 0, stream>>>(W1d, w1d, 1024, 512);
    k_convT<<<gT1, 256, 0, stream>>>(W1r, w1r, 1024, 512);
    dim3 gT2(1024 / 32, 512 / 32);   // W2*: [512,1024]
    k_convT<<<gT2, 256, 0, stream>>>(W2s, w2s, 512, 1024);
    k_convT<<<gT2, 256, 0, stream>>>(W2d, w2d, 512, 1024);
    k_convT<<<gT2, 256, 0, stream>>>(W2r, w2r, 512, 1024);
    dim3 gT3(512 / 32, 512 / 32);    // Wp: [512,512]
    k_convT<<<gT3, 256, 0, stream>>>(Wp, wp, 512, 512);
  }

  int gm = (N + 127) / 128;

  // ---- conv1: x[N,1024] -> fs/fd(bf16), res(f32), width 512 ----
  {
    dim3 g(gm, 512 / 128);
    k_gemm_mfma<unsigned short><<<g, 256, 0, stream>>>(xb, w1s, b1s, fs, N, 1024, 512);
    k_gemm_mfma<unsigned short><<<g, 256, 0, stream>>>(xb, w1d, b1d, fd, N, 1024, 512);
    k_gemm_mfma<float>         <<<g, 256, 0, stream>>>(xb, w1r, b1r, res, N, 1024, 512);
  }
  k_edge_fused<256, false><<<(N + 1) / 2, 256, 0, stream>>>(fs, fd, res, at1, src, offp, elist, h1, N);

  // ---- conv2: h1[N,512] -> width 1024 ----
  {
    dim3 g(gm, 1024 / 128);
    k_gemm_mfma<unsigned short><<<g, 256, 0, stream>>>(h1, w2s, b2s, fs, N, 512, 1024);
    k_gemm_mfma<unsigned short><<<g, 256, 0, stream>>>(h1, w2d, b2d, fd, N, 512, 1024);
    k_gemm_mfma<float>         <<<g, 256, 0, stream>>>(h1, w2r, b2r, res, N, 512, 1024);
  }
  k_edge_fused<512, true><<<(N + 1) / 2, 256, 0, stream>>>(fs, fd, res, at2, src, offp, elist, h2, N);

  // ---- projection: h2[N,512] @ Wp[512,512] + bp -> out (final relu no-op) ----
  {
    dim3 g(gm, 512 / 128);
    k_gemm_mfma<float><<<g, 256, 0, stream>>>(h2, wp, bp, out, N, 512, 512);
  }
}

// Round 3
// 378.593 us; speedup vs baseline: 3.7794x; 1.0961x over previous
//
#include <hip/hip_runtime.h>
#include <math.h>

static constexpr int HEADS = 2;

typedef unsigned int u32;
typedef __attribute__((ext_vector_type(4))) short short4v;
typedef __attribute__((ext_vector_type(8))) short short8v;
typedef __attribute__((ext_vector_type(4))) float f32x4;

__device__ __forceinline__ unsigned short f2b(float f) {
  union { float f; u32 u; } v; v.f = f;
  u32 u = v.u;
  u32 r = (u + 0x7fffu + ((u >> 16) & 1u)) >> 16;  // RNE
  return (unsigned short)r;
}
__device__ __forceinline__ float b2f(unsigned short b) {
  union { u32 u; float f; } v; v.u = ((u32)b) << 16;
  return v.f;
}

__device__ __forceinline__ void async_copy16(const void* g, void* l) {
  __builtin_amdgcn_global_load_lds(
      (const __attribute__((address_space(1))) u32*)g,
      (__attribute__((address_space(3))) u32*)l, 16, 0, 0);
}

// ---------------- CSR build ----------------
__global__ void k_count(const int* __restrict__ dst, int* __restrict__ deg, int E) {
  int t = blockIdx.x * blockDim.x + threadIdx.x;
  if (t < E) atomicAdd(&deg[dst[t]], 1);
}

__global__ void k_scan(const int* __restrict__ deg, int* __restrict__ off, int n) {
  __shared__ int part[1024];
  int t = threadIdx.x;
  int per = (n + 1023) >> 10;
  int s0 = t * per, s1 = min(s0 + per, n);
  int s = 0;
  for (int i = s0; i < s1; ++i) s += deg[i];
  part[t] = s;
  __syncthreads();
  for (int d = 1; d < 1024; d <<= 1) {
    int v = (t >= d) ? part[t - d] : 0;
    __syncthreads();
    part[t] += v;
    __syncthreads();
  }
  int base = (t == 0) ? 0 : part[t - 1];
  for (int i = s0; i < s1; ++i) { off[i] = base; base += deg[i]; }
  if (t == 1023) off[n] = part[1023];
}

__global__ void k_scatter(const int* __restrict__ dst, const int* __restrict__ off,
                          int* __restrict__ cursor, int* __restrict__ elist, int E) {
  int t = blockIdx.x * blockDim.x + threadIdx.x;
  if (t < E) {
    int d = dst[t];
    int p = atomicAdd(&cursor[d], 1);
    elist[off[d] + p] = t;
  }
}

// ---------------- converts ----------------
__global__ void k_f2b(const float* __restrict__ x, unsigned short* __restrict__ xb, int n4) {
  int t = blockIdx.x * blockDim.x + threadIdx.x;
  if (t < n4) {
    float4 v = reinterpret_cast<const float4*>(x)[t];
    short4v o;
    o[0] = (short)f2b(v.x); o[1] = (short)f2b(v.y);
    o[2] = (short)f2b(v.z); o[3] = (short)f2b(v.w);
    reinterpret_cast<short4v*>(xb)[t] = o;
  }
}

// W [K,Ncol] f32 -> Wt [Ncol,K] bf16 (Wt may point into a concatenated buffer)
__global__ __launch_bounds__(256) void k_convT(const float* __restrict__ W,
                                               unsigned short* __restrict__ Wt,
                                               int K, int Ncol) {
  __shared__ float tile[32][33];
  int bx = blockIdx.x * 32;  // Ncol dim
  int by = blockIdx.y * 32;  // K dim
  int tx = threadIdx.x & 31, ty = threadIdx.x >> 5;  // ty 0..7
#pragma unroll
  for (int i = 0; i < 32; i += 8)
    tile[ty + i][tx] = W[(size_t)(by + ty + i) * Ncol + bx + tx];
  __syncthreads();
#pragma unroll
  for (int i = 0; i < 32; i += 8)
    Wt[(size_t)(bx + ty + i) * K + by + tx] = f2b(tile[tx][ty + i]);
}

// ---------------- MFMA GEMM (batched outputs) ----------------
// C_logical[M, Ncol] = A[M,K](bf16) @ Bt[Ncol,K]^T + bias.
// cols [0, nbf)      -> bf16 into Cb[M, nbf]
// cols [nbf, Ncol)   -> f32  into Cf[M, Ncol-nbf]
// 128x128 tile, BK=32, 4 waves (2x2 of 64x64), global_load_lds staging.
__global__ __launch_bounds__(256) void k_gemm_mfma(const unsigned short* __restrict__ A,
                                                   const unsigned short* __restrict__ Bt,
                                                   const float* __restrict__ bias,
                                                   unsigned short* __restrict__ Cb,
                                                   float* __restrict__ Cf,
                                                   int M, int K, int Ncol, int nbf) {
  __shared__ __align__(16) unsigned short As[128 * 32];
  __shared__ __align__(16) unsigned short Bs[128 * 32];
  int t = threadIdx.x;
  int l = t & 63, w = t >> 6;
  int wr = w >> 1, wc = w & 1;
  int bm = blockIdx.x * 128, bn = blockIdx.y * 128;

  f32x4 acc[4][4] = {};

  int srow = t >> 2;            // 0..63
  int scol = (t & 3) * 8;       // bf16 element offset (16B)

  for (int k0 = 0; k0 < K; k0 += 32) {
    __syncthreads();
#pragma unroll
    for (int i = 0; i < 2; ++i) {
      int r = srow + i * 64;
      int gr = bm + r; if (gr >= M) gr = M - 1;
      async_copy16(A + (size_t)gr * K + k0 + scol, As + r * 32 + scol);
      int gb = bn + r;  // Ncol multiple of 128 -> in bounds
      async_copy16(Bt + (size_t)gb * K + k0 + scol, Bs + r * 32 + scol);
    }
    __syncthreads();

    short8v af[4], bf[4];
#pragma unroll
    for (int m = 0; m < 4; ++m)
      af[m] = *reinterpret_cast<const short8v*>(As + (wr * 64 + m * 16 + (l & 15)) * 32 + (l >> 4) * 8);
#pragma unroll
    for (int n = 0; n < 4; ++n)
      bf[n] = *reinterpret_cast<const short8v*>(Bs + (wc * 64 + n * 16 + (l & 15)) * 32 + (l >> 4) * 8);
#pragma unroll
    for (int m = 0; m < 4; ++m)
#pragma unroll
      for (int n = 0; n < 4; ++n)
        acc[m][n] = __builtin_amdgcn_mfma_f32_16x16x32_bf16(af[m], bf[n], acc[m][n], 0, 0, 0);
  }

  bool isbf = (bn < nbf);  // uniform per block (nbf multiple of 128)
#pragma unroll
  for (int m = 0; m < 4; ++m) {
#pragma unroll
    for (int q = 0; q < 4; ++q) {
      int row = bm + wr * 64 + m * 16 + (l >> 4) * 4 + q;
      if (row < M) {
#pragma unroll
        for (int n = 0; n < 4; ++n) {
          int col = bn + wc * 64 + n * 16 + (l & 15);
          float v = acc[m][n][q] + bias[col];
          if (isbf) {
            Cb[(size_t)row * nbf + col] = f2b(v);
          } else {
            Cf[(size_t)row * (Ncol - nbf) + (col - nbf)] = v;
          }
        }
      }
    }
  }
}

// ---------------- fused edge phase ----------------
// f1[N, 2W] bf16: cols [0,W)=fs, [W,2W)=fd.  res[N,W] f32.  attn[H,D] f32.
// One wave per (node, head); edge loop unrolled x4 for MLP.
// SUMH: sum the two heads' relu outputs (conv2 epilogue), write [N,D] bf16;
// else write [N,W] bf16.
template <int D, bool SUMH>
__global__ __launch_bounds__(256) void k_edge_fused(const unsigned short* __restrict__ f1,
                                                    const float* __restrict__ res,
                                                    const float* __restrict__ attn,
                                                    const int* __restrict__ src,
                                                    const int* __restrict__ off,
                                                    const int* __restrict__ elist,
                                                    unsigned short* __restrict__ outb,
                                                    int N) {
  constexpr int W = HEADS * D;
  constexpr int PER = D / 64;
  __shared__ float hs[2][SUMH ? D : 1];

  int w = threadIdx.x >> 6, l = threadIdx.x & 63;
  int node = blockIdx.x * 2 + (w >> 1);
  int h = w & 1;
  bool active = node < N;

  float fdv[PER], av[PER], acc[PER];
  float m = -1e30f, s = 0.f;

  if (active) {
    const unsigned short* pfd = f1 + (size_t)node * (2 * W) + W + h * D + l * PER;
    const float* pa = attn + h * D + l * PER;
#pragma unroll
    for (int j = 0; j < PER; ++j) { fdv[j] = b2f(pfd[j]); av[j] = pa[j]; acc[j] = 0.f; }

    int b = off[node], e = off[node + 1];
    for (int i = b; i < e; i += 4) {
      int sidx[4];
#pragma unroll
      for (int j = 0; j < 4; ++j) {
        int ii = (i + j < e) ? i + j : i;   // dup -> same address, cache hit
        sidx[j] = src[elist[ii]];
      }
      float rowf[4][PER];
#pragma unroll
      for (int j = 0; j < 4; ++j) {
        const unsigned short* p = f1 + (size_t)sidx[j] * (2 * W) + h * D + l * PER;
        if constexpr (PER == 8) {
          short8v rv = *reinterpret_cast<const short8v*>(p);
#pragma unroll
          for (int k = 0; k < PER; ++k) rowf[j][k] = b2f((unsigned short)rv[k]);
        } else {
          short4v rv = *reinterpret_cast<const short4v*>(p);
#pragma unroll
          for (int k = 0; k < PER; ++k) rowf[j][k] = b2f((unsigned short)rv[k]);
        }
      }
      float part[4];
#pragma unroll
      for (int j = 0; j < 4; ++j) {
        float p = 0.f;
#pragma unroll
        for (int k = 0; k < PER; ++k) {
          float v = rowf[j][k] + fdv[k];
          v = v > 0.f ? v : 0.2f * v;
          p += v * av[k];
        }
        part[j] = p;
      }
      // 4 interleaved butterflies: pipelined cross-lane latency
#pragma unroll
      for (int o = 1; o < 64; o <<= 1) {
#pragma unroll
        for (int j = 0; j < 4; ++j) part[j] += __shfl_xor(part[j], o, 64);
      }
      // sequential online-softmax updates (register-resident rows)
#pragma unroll
      for (int j = 0; j < 4; ++j) {
        if (i + j < e) {
          float pj = part[j];
          if (pj <= m) {
            float p = __expf(pj - m);
            s += p;
#pragma unroll
            for (int k = 0; k < PER; ++k) acc[k] += p * rowf[j][k];
          } else {
            float c = (m == -1e30f) ? 0.f : __expf(m - pj);
            s = s * c + 1.f;
#pragma unroll
            for (int k = 0; k < PER; ++k) acc[k] = acc[k] * c + rowf[j][k];
            m = pj;
          }
        }
      }
    }

    float inv = (s > 0.f) ? 1.f / s : 0.f;
    const float* pr = res + (size_t)node * W + h * D + l * PER;
#pragma unroll
    for (int j = 0; j < PER; ++j) {
      float v = acc[j] * inv + pr[j];
      acc[j] = v > 0.f ? v : 0.f;  // relu
    }
  }

  if constexpr (SUMH) {
    if (active && h == 0) {
#pragma unroll
      for (int j = 0; j < PER; ++j) hs[w >> 1][l * PER + j] = acc[j];
    }
    __syncthreads();
    if (active && h == 1) {
      short8v o;
#pragma unroll
      for (int j = 0; j < PER; ++j) o[j] = (short)f2b(acc[j] + hs[w >> 1][l * PER + j]);
      *reinterpret_cast<short8v*>(outb + (size_t)node * D + l * PER) = o;
    }
  } else {
    if (active) {
      short4v o;
#pragma unroll
      for (int j = 0; j < PER; ++j) o[j] = (short)f2b(acc[j]);
      *reinterpret_cast<short4v*>(outb + (size_t)node * W + h * D + l * PER) = o;
    }
  }
}

extern "C" void kernel_launch(void* const* d_in, const int* in_sizes, int n_in,
                              void* d_out, int out_size, void* d_ws, size_t ws_size,
                              hipStream_t stream) {
  const float* x    = (const float*)d_in[0];
  const int*   src  = (const int*)d_in[1];
  const int*   dst  = (const int*)d_in[2];
  const float* W1s  = (const float*)d_in[3];
  const float* b1s  = (const float*)d_in[4];
  const float* W1d  = (const float*)d_in[5];
  const float* b1d  = (const float*)d_in[6];
  const float* at1  = (const float*)d_in[7];
  const float* W1r  = (const float*)d_in[8];
  const float* b1r  = (const float*)d_in[9];
  const float* W2s  = (const float*)d_in[10];
  const float* b2s  = (const float*)d_in[11];
  const float* W2d  = (const float*)d_in[12];
  const float* b2d  = (const float*)d_in[13];
  const float* at2  = (const float*)d_in[14];
  const float* W2r  = (const float*)d_in[15];
  const float* b2r  = (const float*)d_in[16];
  const float* Wp   = (const float*)d_in[17];
  const float* bp   = (const float*)d_in[18];
  float* out = (float*)d_out;

  const int N = in_sizes[0] / 1024;  // 10000
  const int E = in_sizes[1];         // 160000

  // ---- workspace layout ----
  char* ws = (char*)d_ws;
  size_t o = 0;
  auto alloc = [&](size_t bytes) { char* p = ws + o; o += (bytes + 255) & ~(size_t)255; return p; };
  unsigned short* xb    = (unsigned short*)alloc((size_t)N * 1024 * 2);
  unsigned short* w1cat = (unsigned short*)alloc((size_t)1536 * 1024 * 2);  // [3*512, 1024]
  unsigned short* w2cat = (unsigned short*)alloc((size_t)3072 * 512 * 2);   // [3*1024, 512]
  unsigned short* wp    = (unsigned short*)alloc((size_t)512 * 512 * 2);
  float*          bias1 = (float*)alloc(1536 * 4);
  float*          bias2 = (float*)alloc(3072 * 4);
  unsigned short* f1    = (unsigned short*)alloc((size_t)N * 2048 * 2);  // fs||fd, sized for conv2
  float*          res   = (float*)alloc((size_t)N * 1024 * 4);
  unsigned short* h1    = (unsigned short*)alloc((size_t)N * 512 * 2);
  unsigned short* h2    = (unsigned short*)alloc((size_t)N * 512 * 2);
  int* deg    = (int*)alloc((size_t)N * 4);
  int* offp   = (int*)alloc((size_t)(N + 1) * 4);
  int* cursor = (int*)alloc((size_t)N * 4);
  int* elist  = (int*)alloc((size_t)E * 4);
  if (o > ws_size) return;

  // ---- CSR build ----
  hipMemsetAsync(deg, 0, (size_t)N * 4, stream);
  hipMemsetAsync(cursor, 0, (size_t)N * 4, stream);
  k_count<<<(E + 255) / 256, 256, 0, stream>>>(dst, deg, E);
  k_scan<<<1, 1024, 0, stream>>>(deg, offp, N);
  k_scatter<<<(E + 255) / 256, 256, 0, stream>>>(dst, offp, cursor, elist, E);

  // ---- converts ----
  k_f2b<<<((N * 1024 / 4) + 255) / 256, 256, 0, stream>>>(x, xb, N * 1024 / 4);
  {
    dim3 gT1(512 / 32, 1024 / 32);   // W1*: [1024,512] -> [512,1024]
    k_convT<<<gT1, 256, 0, stream>>>(W1s, w1cat + (size_t)0 * 1024, 1024, 512);
    k_convT<<<gT1, 256, 0, stream>>>(W1d, w1cat + (size_t)512 * 1024, 1024, 512);
    k_convT<<<gT1, 256, 0, stream>>>(W1r, w1cat + (size_t)1024 * 1024, 1024, 512);
    dim3 gT2(1024 / 32, 512 / 32);   // W2*: [512,1024] -> [1024,512]
    k_convT<<<gT2, 256, 0, stream>>>(W2s, w2cat + (size_t)0 * 512, 512, 1024);
    k_convT<<<gT2, 256, 0, stream>>>(W2d, w2cat + (size_t)1024 * 512, 512, 1024);
    k_convT<<<gT2, 256, 0, stream>>>(W2r, w2cat + (size_t)2048 * 512, 512, 1024);
    dim3 gT3(512 / 32, 512 / 32);
    k_convT<<<gT3, 256, 0, stream>>>(Wp, wp, 512, 512);
  }
  hipMemcpyAsync(bias1 + 0,    b1s, 512 * 4, hipMemcpyDeviceToDevice, stream);
  hipMemcpyAsync(bias1 + 512,  b1d, 512 * 4, hipMemcpyDeviceToDevice, stream);
  hipMemcpyAsync(bias1 + 1024, b1r, 512 * 4, hipMemcpyDeviceToDevice, stream);
  hipMemcpyAsync(bias2 + 0,    b2s, 1024 * 4, hipMemcpyDeviceToDevice, stream);
  hipMemcpyAsync(bias2 + 1024, b2d, 1024 * 4, hipMemcpyDeviceToDevice, stream);
  hipMemcpyAsync(bias2 + 2048, b2r, 1024 * 4, hipMemcpyDeviceToDevice, stream);

  int gm = (N + 127) / 128;

  // ---- conv1: [N,1024] @ [1024,1536] -> f1[N,1024] bf16 + res[N,512] f32 ----
  k_gemm_mfma<<<dim3(gm, 1536 / 128), 256, 0, stream>>>(xb, w1cat, bias1, f1, res,
                                                        N, 1024, 1536, 1024);
  k_edge_fused<256, false><<<(N + 1) / 2, 256, 0, stream>>>(f1, res, at1, src, offp, elist, h1, N);

  // ---- conv2: [N,512] @ [512,3072] -> f1[N,2048] bf16 + res[N,1024] f32 ----
  k_gemm_mfma<<<dim3(gm, 3072 / 128), 256, 0, stream>>>(h1, w2cat, bias2, f1, res,
                                                        N, 512, 3072, 2048);
  k_edge_fused<512, true><<<(N + 1) / 2, 256, 0, stream>>>(f1, res, at2, src, offp, elist, h2, N);

  // ---- projection: h2[N,512] @ [512,512] -> out f32 (final relu no-op) ----
  k_gemm_mfma<<<dim3(gm, 512 / 128), 256, 0, stream>>>(h2, wp, bp, (unsigned short*)nullptr, out,
                                                       N, 512, 512, 0);
}